// Round 8
// baseline (367.307 us; speedup 1.0000x reference)
//
#include <hip/hip_runtime.h>

// ---------------------------------------------------------------------------
// 3-layer GCN forward. out[d] = relu( dinv[d]*( sum_{s->d} g[s] + g[d] ) + b ),
// g = (x@W)*dinv stored bf16 (halves random-gather traffic; f32 accum).
// Layer-1 GEMM: split-bf16 MFMA (x = hi+lo, 3 passes => ~f32 accuracy).
// Layers 2/3 GEMMs are FUSED into the aggregation epilogue as a per-node
// matvec (W staged in LDS, y broadcast via shuffles) -> no Xb buffer, no
// separate GEMM kernels. Gathers are uint4 (16B/lane, OF/8 lanes per edge).
// CSR built per call via two-level counting sort (bucket = dst>>9), packed u32.
// ---------------------------------------------------------------------------

#define BSH 9                 // 512 nodes per bucket
#define BNODES (1 << BSH)

typedef __attribute__((ext_vector_type(8))) short bf16x8;
typedef __attribute__((ext_vector_type(4))) float f32x4;

__device__ inline ushort f2bf(float x) {   // round-to-nearest-even f32->bf16
    uint u = __float_as_uint(x);
    return (ushort)((u + 0x7fffu + ((u >> 16) & 1u)) >> 16);
}
__device__ inline float bf2f(ushort h) { return __uint_as_float(((uint)h) << 16); }
__device__ inline void split2(float x, ushort& h, ushort& l) {
    ushort hh = f2bf(x);
    h = hh;
    l = f2bf(x - bf2f(hh));
}

// fused: bucket histogram of dst (blocks < HB) + W1 split/transpose
__global__ __launch_bounds__(256) void k_pre(
    const int* __restrict__ dst, int* __restrict__ bcnt, int E, int HB,
    const float* __restrict__ W1,
    ushort* __restrict__ Wh1, ushort* __restrict__ Wl1)
{
    if ((int)blockIdx.x < HB) {
        __shared__ int h[256];
        int t = threadIdx.x;
        h[t] = 0;
        __syncthreads();
        for (int i = blockIdx.x * 256 + t; i < E; i += HB * 256)
            atomicAdd(&h[dst[i] >> BSH], 1);
        __syncthreads();
        if (h[t]) atomicAdd(&bcnt[t], h[t]);
        return;
    }
    int i = (blockIdx.x - HB) * 256 + threadIdx.x;   // exactly 16384 = 64 blocks
    int k = i >> 6, n = i & 63;
    ushort h, l;
    split2(W1[i], h, l);
    Wh1[n * 256 + k] = h;
    Wl1[n * 256 + k] = l;
}

// scan bucket counts -> boff (exclusive), init bcur. NB <= 1024.
__global__ __launch_bounds__(1024) void k_bscan(const int* __restrict__ bcnt,
                                                int* __restrict__ boff,
                                                int* __restrict__ bcur, int NB) {
    __shared__ int s[1024];
    int t = threadIdx.x;
    int v = (t < NB) ? bcnt[t] : 0;
    s[t] = v;
    __syncthreads();
    for (int off = 1; off < 1024; off <<= 1) {
        int a = (t >= off) ? s[t - off] : 0;
        __syncthreads();
        s[t] += a;
        __syncthreads();
    }
    if (t < NB) {
        int ex = s[t] - v;
        boff[t] = ex;
        bcur[t] = ex;
    }
    if (t == NB - 1) boff[NB] = s[t];
}

// partition edges into bucket-contiguous packed (local_dst<<23 | src) words
template <int CH>
__global__ __launch_bounds__(256) void k_part(const int* __restrict__ src,
                                              const int* __restrict__ dst,
                                              int* __restrict__ bcur,
                                              uint* __restrict__ pairs,
                                              int E, int NB) {
    __shared__ int lh[256];
    __shared__ int lbase[256];
    const int t = threadIdx.x;
    const int e0 = blockIdx.x * CH;
    const int n = min(CH, E - e0);

    lh[t] = 0;
    __syncthreads();
    for (int i = t; i < n; i += 256) atomicAdd(&lh[dst[e0 + i] >> BSH], 1);
    __syncthreads();
    if (t < NB && lh[t] > 0) lbase[t] = atomicAdd(&bcur[t], lh[t]);
    __syncthreads();
    lh[t] = 0;
    __syncthreads();
    for (int i = t; i < n; i += 256) {
        int d = dst[e0 + i];
        int b = d >> BSH;
        int r = atomicAdd(&lh[b], 1);
        pairs[(long)lbase[b] + r] = ((uint)(d & (BNODES - 1)) << 23) | (uint)src[e0 + i];
    }
}

// per-bucket: per-node histogram + scan (LDS), emit row_off/dinv, scatter esrc
__global__ __launch_bounds__(1024) void k_bucket(const uint* __restrict__ pairs,
                                                 const int* __restrict__ boff,
                                                 int* __restrict__ row_off,
                                                 float* __restrict__ dinv,
                                                 int* __restrict__ esrc,
                                                 int N, int NB, int E) {
    __shared__ int cnt[BNODES];
    __shared__ int sc[BNODES];
    __shared__ int cur[BNODES];
    const int b = blockIdx.x;
    const int t = threadIdx.x;
    const int base = b << BSH;
    const int nn = min(BNODES, N - base);
    const int ebase = boff[b], eend = boff[b + 1];

    if (t < BNODES) cnt[t] = 0;
    __syncthreads();
    for (int e = ebase + t; e < eend; e += 1024)
        atomicAdd(&cnt[pairs[e] >> 23], 1);
    __syncthreads();
    if (t < BNODES) sc[t] = cnt[t];
    __syncthreads();
    for (int off = 1; off < BNODES; off <<= 1) {
        int a = (t < BNODES && t >= off) ? sc[t - off] : 0;
        __syncthreads();
        if (t < BNODES) sc[t] += a;
        __syncthreads();
    }
    if (t < nn) {
        int ex = sc[t] - cnt[t];
        row_off[base + t] = ebase + ex;
        cur[t] = ex;
        dinv[base + t] = rsqrtf((float)(cnt[t] + 1));
    }
    if (b == NB - 1 && t == 0) row_off[N] = E;
    __syncthreads();
    for (int e = ebase + t; e < eend; e += 1024) {
        uint p = pairs[e];
        int r = atomicAdd(&cur[p >> 23], 1);
        esrc[ebase + r] = (int)(p & 0x7fffffu);
    }
}

// ---------------------------------------------------------------------------
// Split-bf16 MFMA GEMM (layer 1 only): G[n] = bf16( (X[row(n)] @ W) * dinv[n] ).
// Block = 64 rows x OF cols, 4 waves (16 rows each), BK=32 per step.
// ---------------------------------------------------------------------------
template <int K, int OF>
__global__ __launch_bounds__(256) void k_mfma(
    const float* __restrict__ X, int sx,
    const int* __restrict__ nodes,          // may be null (identity)
    const ushort* __restrict__ Wh,          // [OF][K] bf16
    const ushort* __restrict__ Wl,
    const float* __restrict__ dinv,
    ushort* __restrict__ G,                 // bf16, packed stride OF
    int N)
{
    constexpr int BM = 64, BK = 32, LDF = 40;
    constexpr int NT = OF / 16;             // MFMA col tiles
    __shared__ ushort Ah[BM * LDF], Al[BM * LDF];
    __shared__ ushort Bh[OF * LDF], Bl[OF * LDF];

    const int tid = threadIdx.x;
    const int l = tid & 63;
    const int w = tid >> 6;                 // wave id: rows w*16..w*16+15
    const int m0 = blockIdx.x * BM;
    const int lm = l & 15, kg = l >> 4;

    f32x4 acc[NT];
#pragma unroll
    for (int nt = 0; nt < NT; ++nt) acc[nt] = (f32x4){0.f, 0.f, 0.f, 0.f};

    for (int k0 = 0; k0 < K; k0 += BK) {
        __syncthreads();
#pragma unroll
        for (int t = 0; t < 2; ++t) {
            int i = tid + t * 256;
            int m = i >> 3, kq = i & 7;
            float4 v = make_float4(0.f, 0.f, 0.f, 0.f);
            if (m0 + m < N) {
                long row = nodes ? (long)nodes[m0 + m] : (long)(m0 + m);
                v = *reinterpret_cast<const float4*>(X + row * (long)sx + k0 + kq * 4);
            }
            ushort4 hh, ll;
            split2(v.x, hh.x, ll.x); split2(v.y, hh.y, ll.y);
            split2(v.z, hh.z, ll.z); split2(v.w, hh.w, ll.w);
            *reinterpret_cast<ushort4*>(&Ah[m * LDF + kq * 4]) = hh;
            *reinterpret_cast<ushort4*>(&Al[m * LDF + kq * 4]) = ll;
        }
        for (int i = tid; i < OF * 16; i += 256) {
            int n = i >> 4, ku = i & 15;
            *reinterpret_cast<uint*>(&Bh[n * LDF + ku * 2]) =
                *reinterpret_cast<const uint*>(Wh + (long)n * K + k0 + ku * 2);
            *reinterpret_cast<uint*>(&Bl[n * LDF + ku * 2]) =
                *reinterpret_cast<const uint*>(Wl + (long)n * K + k0 + ku * 2);
        }
        __syncthreads();

        bf16x8 ah = *reinterpret_cast<bf16x8*>(&Ah[(w * 16 + lm) * LDF + kg * 8]);
        bf16x8 al = *reinterpret_cast<bf16x8*>(&Al[(w * 16 + lm) * LDF + kg * 8]);
#pragma unroll
        for (int nt = 0; nt < NT; ++nt) {
            bf16x8 bh = *reinterpret_cast<bf16x8*>(&Bh[(nt * 16 + lm) * LDF + kg * 8]);
            bf16x8 bl = *reinterpret_cast<bf16x8*>(&Bl[(nt * 16 + lm) * LDF + kg * 8]);
            acc[nt] = __builtin_amdgcn_mfma_f32_16x16x32_bf16(al, bh, acc[nt], 0, 0, 0);
            acc[nt] = __builtin_amdgcn_mfma_f32_16x16x32_bf16(ah, bl, acc[nt], 0, 0, 0);
            acc[nt] = __builtin_amdgcn_mfma_f32_16x16x32_bf16(ah, bh, acc[nt], 0, 0, 0);
        }
    }
#pragma unroll
    for (int r = 0; r < 4; ++r) {
        int m = m0 + w * 16 + kg * 4 + r;
        if (m < N) {
            float dv = dinv[m];
#pragma unroll
            for (int nt = 0; nt < NT; ++nt)
                G[(long)m * OF + nt * 16 + lm] = f2bf(acc[nt][r] * dv);
        }
    }
}

// ---------------------------------------------------------------------------
// Fused CSR aggregation + epilogue + NEXT-layer matvec.
// One wave per node; OF/8 lanes per edge, each lane one uint4 (8 bf16).
// After reducing y[n] (this layer's activation), all 64 lanes compute
// g_next[n][j] = dinv[n] * sum_k y[k]*Wn[k][j]  (Wn staged in LDS; y
// broadcast via shuffles from the OF/8 sub==0 lanes). ON==0 -> final layer:
// write y to f32 output instead.
// ---------------------------------------------------------------------------
#define UNPK8(A, W)                                       \
    A[0] += __uint_as_float((W).x << 16);                 \
    A[1] += __uint_as_float((W).x & 0xffff0000u);         \
    A[2] += __uint_as_float((W).y << 16);                 \
    A[3] += __uint_as_float((W).y & 0xffff0000u);         \
    A[4] += __uint_as_float((W).z << 16);                 \
    A[5] += __uint_as_float((W).z & 0xffff0000u);         \
    A[6] += __uint_as_float((W).w << 16);                 \
    A[7] += __uint_as_float((W).w & 0xffff0000u);

template <int OF, int ON>
__global__ __launch_bounds__(256) void k_aggf(
    const int* __restrict__ row_off, const int* __restrict__ esrc,
    const uint4* __restrict__ g,        // gather table, row = OF/8 uint4
    const float* __restrict__ dinv,
    const float* __restrict__ bias,     // this layer's bias [OF]
    const float* __restrict__ Wn,       // next W [OF][ON] f32 (unused if ON==0)
    ushort* __restrict__ gnext,         // next messages bf16 (if ON>0)
    float* __restrict__ yout,           // final output f32 (if ON==0)
    int N)
{
    constexpr int WPE = OF / 8;         // lanes per edge
    constexpr int EPW = 64 / WPE;       // edges in parallel per wave
    __shared__ float Wl[ON == 0 ? 1 : OF * ON];

    if constexpr (ON > 0) {
        for (int i = threadIdx.x; i < OF * ON; i += 256) Wl[i] = Wn[i];
        __syncthreads();
    }

    const int lane = threadIdx.x & 63;
    const int q = lane % WPE;           // feature octet
    const int sub = lane / WPE;
    const int n = blockIdx.x * (blockDim.x >> 6) + (threadIdx.x >> 6);
    if (n >= N) return;
    const int start = row_off[n], end = row_off[n + 1];
    const float dv = dinv[n];

    float ac[4][8];
#pragma unroll
    for (int u = 0; u < 4; ++u)
#pragma unroll
        for (int j = 0; j < 8; ++j) ac[u][j] = 0.f;

    int e = start + sub;
    for (; e + 3 * EPW < end; e += 4 * EPW) {
        int s[4];
#pragma unroll
        for (int u = 0; u < 4; ++u) s[u] = esrc[e + u * EPW];
        uint4 w[4];
#pragma unroll
        for (int u = 0; u < 4; ++u) w[u] = g[(long)s[u] * WPE + q];
#pragma unroll
        for (int u = 0; u < 4; ++u) { UNPK8(ac[u], w[u]); }
    }
    for (; e < end; e += EPW) {
        uint4 w = g[(long)esrc[e] * WPE + q];
        UNPK8(ac[0], w);
    }

    float tot[8];
#pragma unroll
    for (int j = 0; j < 8; ++j)
        tot[j] = (ac[0][j] + ac[1][j]) + (ac[2][j] + ac[3][j]);
#pragma unroll
    for (int m = WPE; m < 64; m <<= 1)
#pragma unroll
        for (int j = 0; j < 8; ++j) tot[j] += __shfl_xor(tot[j], m, 64);

    // epilogue on sub==0 lanes: self-loop + dinv + bias + relu
    float yv[8];
#pragma unroll
    for (int j = 0; j < 8; ++j) yv[j] = 0.f;
    if (sub == 0) {
        uint4 sv = g[(long)n * WPE + q];
        float sl[8];
        sl[0] = __uint_as_float(sv.x << 16); sl[1] = __uint_as_float(sv.x & 0xffff0000u);
        sl[2] = __uint_as_float(sv.y << 16); sl[3] = __uint_as_float(sv.y & 0xffff0000u);
        sl[4] = __uint_as_float(sv.z << 16); sl[5] = __uint_as_float(sv.z & 0xffff0000u);
        sl[6] = __uint_as_float(sv.w << 16); sl[7] = __uint_as_float(sv.w & 0xffff0000u);
        float4 b0 = *reinterpret_cast<const float4*>(bias + q * 8);
        float4 b1 = *reinterpret_cast<const float4*>(bias + q * 8 + 4);
        float bb[8] = {b0.x, b0.y, b0.z, b0.w, b1.x, b1.y, b1.z, b1.w};
#pragma unroll
        for (int j = 0; j < 8; ++j)
            yv[j] = fmaxf(fmaf(tot[j] + sl[j], dv, bb[j]), 0.f);
    }

    if constexpr (ON == 0) {
        if (sub == 0) {
            float4 o0 = {yv[0], yv[1], yv[2], yv[3]};
            float4 o1 = {yv[4], yv[5], yv[6], yv[7]};
            *reinterpret_cast<float4*>(yout + (long)n * OF + q * 8) = o0;
            *reinterpret_cast<float4*>(yout + (long)n * OF + q * 8 + 4) = o1;
        }
    } else {
        // matvec: g_next[j] = dv * sum_k y[k] * Wn[k][j]
        constexpr int GRP = 64 / ON;
        constexpr int KR = OF / GRP;
        const int j = lane % ON, kg = lane / ON;
        float a2 = 0.f;
#pragma unroll
        for (int kk = 0; kk < KR; ++kk) {
            float yk = __shfl(yv[kk & 7], (kg * KR + kk) >> 3, 64);
            a2 = fmaf(yk, Wl[(kg * KR + kk) * ON + j], a2);
        }
#pragma unroll
        for (int m = ON; m < 64; m <<= 1) a2 += __shfl_xor(a2, m, 64);
        if (lane < ON) gnext[(long)n * ON + j] = f2bf(a2 * dv);
    }
}

extern "C" void kernel_launch(void* const* d_in, const int* in_sizes, int n_in,
                              void* d_out, int out_size, void* d_ws, size_t ws_size,
                              hipStream_t stream) {
    const int*   nodes = (const int*)d_in[0];
    const int*   edges = (const int*)d_in[1];
    const float* emb   = (const float*)d_in[2];
    const float* W1    = (const float*)d_in[3];
    const float* b1    = (const float*)d_in[4];
    const float* W2    = (const float*)d_in[5];
    const float* b2    = (const float*)d_in[6];
    const float* W3    = (const float*)d_in[7];
    const float* b3    = (const float*)d_in[8];

    const int N = in_sizes[0];
    const int E = in_sizes[1] / 2;
    const int* src  = edges;
    const int* dstv = edges + E;
    const int NB = (N + BNODES - 1) >> BSH;   // 196 for N=100000

    char* ws = (char*)d_ws;
    size_t off = 0;
    auto alloc = [&](size_t bytes) {
        char* p = ws + off;
        off += (bytes + 255) & ~(size_t)255;
        return p;
    };
    float* dinv    = (float*)alloc((size_t)N * 4);
    int*   row_off = (int*)  alloc((size_t)(N + 1) * 4);
    int*   bcnt    = (int*)  alloc((size_t)(NB + 1) * 4);
    int*   boff    = (int*)  alloc((size_t)(NB + 1) * 4);
    int*   bcur    = (int*)  alloc((size_t)NB * 4);
    int*   esrc    = (int*)  alloc((size_t)E * 4);
    size_t shsz    = (size_t)E * 4 > (size_t)N * 128 ? (size_t)E * 4 : (size_t)N * 128;
    char*  shared_region = alloc(shsz);            // pairs u32 (12.8MB) / G1 bf16 (12.8MB)
    uint*  pairs   = (uint*)shared_region;
    ushort* G1     = (ushort*)shared_region;
    ushort* G2     = (ushort*)alloc((size_t)N * 32 * 2);
    ushort* G3     = (ushort*)alloc((size_t)N * 16 * 2);
    ushort* Wh1 = (ushort*)alloc(16384 * 2), *Wl1 = (ushort*)alloc(16384 * 2);
    float* out     = (float*)d_out;

    // --- CSR build + dinv + W1 prep ---
    constexpr int CH = 4096;
    constexpr int HB = 1024;              // histogram blocks in k_pre
    const int nch = (E + CH - 1) / CH;
    hipMemsetAsync(bcnt, 0, (size_t)NB * 4, stream);
    hipLaunchKernelGGL(k_pre, dim3(HB + 64), dim3(256), 0, stream,
                       dstv, bcnt, E, HB, W1, Wh1, Wl1);
    hipLaunchKernelGGL(k_bscan,  dim3(1), dim3(1024), 0, stream, bcnt, boff, bcur, NB);
    hipLaunchKernelGGL((k_part<CH>), dim3(nch), dim3(256), 0, stream,
                       src, dstv, bcur, pairs, E, NB);
    hipLaunchKernelGGL(k_bucket, dim3(NB), dim3(1024), 0, stream,
                       pairs, boff, row_off, dinv, esrc, N, NB, E);

    const int gb = (N + 63) / 64;
    const int ab = (N + 3) / 4;   // 4 waves / block

    // --- layer 1 GEMM: 256 -> 64 ---  (G1 overwrites pairs; dead after k_bucket)
    hipLaunchKernelGGL((k_mfma<256, 64>), dim3(gb), dim3(256), 0, stream,
                       emb, 256, nodes, Wh1, Wl1, dinv, G1, N);
    // --- agg1 + fused GEMM2 (64 -> 32) ---
    hipLaunchKernelGGL((k_aggf<64, 32>), dim3(ab), dim3(256), 0, stream,
                       row_off, esrc, (const uint4*)G1, dinv, b1, W2, G2,
                       (float*)nullptr, N);
    // --- agg2 + fused GEMM3 (32 -> 16) ---
    hipLaunchKernelGGL((k_aggf<32, 16>), dim3(ab), dim3(256), 0, stream,
                       row_off, esrc, (const uint4*)G2, dinv, b2, W3, G3,
                       (float*)nullptr, N);
    // --- agg3 (final, writes f32 out) ---
    hipLaunchKernelGGL((k_aggf<16, 0>), dim3(ab), dim3(256), 0, stream,
                       row_off, esrc, (const uint4*)G3, dinv, b3,
                       (const float*)nullptr, (ushort*)nullptr, out, N);
}